// Round 12
// baseline (141.227 us; speedup 1.0000x reference)
//
#include <hip/hip_runtime.h>
#include <cmath>

// SpikingLayer forward — dynamic producer/consumer; COALESCED producer loads
// via LDS transpose staging (round-2 mechanics), round-11 consumer verbatim.
//
// vmem[t] = sum_{k<100} (am^k - as^k) x[t-k] (exact truncated-FIR via dual
// 1st-order f64 recurrences; time-chunked, 288-step zero-history warmup =
// mathematically exact after 100 steps). The nonlinear refractory scan is
// NEVER chunked: wave 3 runs it sequentially per neuron in f64, gold op
// order (rounds 5/8/9/10/11 all absmax 0.0 with this math).
//
// Round-11 post-mortem: consumer micro-opts changed nothing -> the wall is
// producer-side L1 TRANSACTION pressure: per-lane loads at 4KB stride = 64
// cache lines per float4 instruction (~52K transactions/CU ~ 22us) plus
// exposed latency. Round-12 delta (single variable):
//   * Producer tile loads are COALESCED (8 lanes cover one neuron row's
//     128B; 16 lines per instruction, 4x fewer transactions), staged
//     through per-producer LDS [64][36] f32, then read per-lane as b128.
//     Chain consumes identical values in identical order (gold preserved).
//   * RING 4->2 so ring (33.8KB) + stage (27.6KB) = 61.6KB keeps 2 WG/CU.
// Consumer: r11 verbatim (8-chunk reg pipeline, direct global stores).

#define T_LEN   1024
#define NT      32
#define RING    2
#define VROWW   33                        // doubles per vmem row (264 B)
#define VSLOTD  (64 * VROWW)              // 2112 doubles per ring slot
#define SROWW   36                        // stage row stride (floats)
#define STAGEW  (64 * SROWW)              // 2304 floats per stage buffer
#define LDS_STG (RING * VSLOTD * 8)       // 33792
#define LDS_FLG (LDS_STG + 3 * STAGEW * 4)// 61440
#define LDS_TOT (LDS_FLG + 33 * 4)        // 61572 B -> 2 WG/CU

__global__ __launch_bounds__(256, 2)
void spiking_fwd(const float* __restrict__ x, const float* __restrict__ rk,
                 float* __restrict__ out,
                 double a_m, double a_s, double am100, double as100)
{
    __shared__ __align__(16) unsigned char lds[LDS_TOT];
    int* const flags = (int*)(lds + LDS_FLG);   // [0..31] tile-ready
    int* const consp = flags + NT;              // tiles consumed

    const int tid = threadIdx.x, wid = tid >> 6, lane = tid & 63;
    const int n0 = blockIdx.x * 64;
    const unsigned vsw = (lane >> 4) & 3;       // vmem bank swizzle (r9-proven)

    if (tid <= NT) flags[tid] = 0;
    __syncthreads();

    if (wid < 3) {
        // ===================== producer (gold math) =====================
        // chunks [0,544) [544,800) [800,1024), warmup 288 for P1/P2
        int pwarm = 0, ptot = 0, pt0 = 0, gt0 = 0;
        if (wid == 0) { pt0 = 0;   ptot = 17; pwarm = 0; gt0 = 0;  }
        if (wid == 1) { pt0 = 256; ptot = 17; pwarm = 9; gt0 = 8;  }
        if (wid == 2) { pt0 = 512; ptot = 16; pwarm = 9; gt0 = 16; }
        const float* xbase = x + (size_t)n0 * T_LEN + pt0;   // block base
        const int rowq = lane >> 3, colq = lane & 7;
        float* const stg = (float*)(lds + LDS_STG) + wid * STAGEW;

        // stage tile 0 (coalesced: 8 lanes cover 128B of one neuron row)
        float4 g[8];
        #pragma unroll
        for (int j = 0; j < 8; ++j)
            g[j] = *(const float4*)(xbase + (size_t)(rowq + 8*j) * T_LEN + colq * 4);
        #pragma unroll
        for (int j = 0; j < 8; ++j)
            *(float4*)(stg + (rowq + 8*j) * SROWW + colq * 4) = g[j];

        double s_m = 0.0, s_s = 0.0;
        unsigned b0 = 0, b1 = 0, b2 = 0, b3 = 0;   // bit FIFO: tiles li-4..li-1

        for (int li = 0; li < ptot; ++li) {
            // per-lane read of own neuron's 32 steps (tile li)
            float4 xc4[8];
            const float* srow = stg + lane * SROWW;
            #pragma unroll
            for (int gq = 0; gq < 8; ++gq)
                xc4[gq] = *(const float4*)(srow + gq * 4);

            // issue coalesced prefetch of tile li+1 (lands under the chain)
            if (li + 1 < ptot) {
                #pragma unroll
                for (int j = 0; j < 8; ++j)
                    g[j] = *(const float4*)(xbase + (size_t)(rowq + 8*j) * T_LEN
                                            + (li + 1) * 32 + colq * 4);
            }

            // step t=pt0+li*32+k needs x[t-100]: k<4 -> tile li-4 bit 28+k,
            // k>=4 -> tile li-3 bit k-4.
            const unsigned wmask = (b0 >> 28) | (b1 << 4);
            unsigned bcur = 0;
            const int gt = gt0 + li;
            const float* xcf = (const float*)xc4;

            if (li >= pwarm) {
                while (gt - __hip_atomic_load(consp, __ATOMIC_ACQUIRE,
                                              __HIP_MEMORY_SCOPE_WORKGROUP) >= RING)
                    __builtin_amdgcn_s_sleep(1);
                double* vrow = (double*)lds
                             + (size_t)(gt & (RING-1)) * VSLOTD + (size_t)lane * VROWW;
                #pragma unroll
                for (int k = 0; k < 32; ++k) {
                    const float  xf = xcf[k];
                    const double xc = (double)xf;
                    const unsigned bd = (wmask >> k) & 1u;
                    s_m = fma(a_m, s_m, xc - (bd ? am100 : 0.0));
                    s_s = fma(a_s, s_s, xc - (bd ? as100 : 0.0));
                    vrow[k ^ vsw] = s_m - s_s;        // swizzled store
                    if (xf != 0.0f) bcur |= (1u << k);
                }
                __hip_atomic_store(&flags[gt], 1, __ATOMIC_RELEASE,
                                   __HIP_MEMORY_SCOPE_WORKGROUP);
            } else {                            // warmup tile
                #pragma unroll
                for (int k = 0; k < 32; ++k) {
                    const float  xf = xcf[k];
                    const double xc = (double)xf;
                    const unsigned bd = (wmask >> k) & 1u;
                    s_m = fma(a_m, s_m, xc - (bd ? am100 : 0.0));
                    s_s = fma(a_s, s_s, xc - (bd ? as100 : 0.0));
                    if (xf != 0.0f) bcur |= (1u << k);
                }
            }
            b0 = b1; b1 = b2; b2 = b3; b3 = bcur;

            // stage the prefetched tile (read of tile li already done above)
            if (li + 1 < ptot) {
                #pragma unroll
                for (int j = 0; j < 8; ++j)
                    *(float4*)(stg + (rowq + 8*j) * SROWW + colq * 4) = g[j];
            }
        }
    } else {
        // ====== consumer: gold r-scan, 8-chunk pipeline, direct stores ======
        const double alpha = (double)rk[1] / (double)rk[0];
        double r = 0.0;
        float* const gdst0 = out + (size_t)(n0 + lane) * T_LEN;

#define STEP1(VMV, OO) do {                                   \
            double v_ = (VMV) - r;                            \
            double n_ = fmax(floor(v_), 0.0);                 \
            r = (r + n_) * alpha;                             \
            OO = (float)n_;                                   \
        } while (0)

#define PREF(VM, H) do {                                      \
            _Pragma("unroll")                                 \
            for (int k2 = 0; k2 < 8; ++k2)                    \
                (VM)[k2] = vrow[((H)*8 + k2) ^ vsw];          \
        } while (0)

#define SCANCH(VM, H) do {                                    \
            float4 o0, o1;                                    \
            STEP1((VM)[0], o0.x); STEP1((VM)[1], o0.y);       \
            STEP1((VM)[2], o0.z); STEP1((VM)[3], o0.w);       \
            STEP1((VM)[4], o1.x); STEP1((VM)[5], o1.y);       \
            STEP1((VM)[6], o1.z); STEP1((VM)[7], o1.w);       \
            *(float4*)(gdst + (H)*8)     = o0;                \
            *(float4*)(gdst + (H)*8 + 4) = o1;                \
        } while (0)

        for (int gt = 0; gt < NT; ++gt) {
            while (!__hip_atomic_load(&flags[gt], __ATOMIC_ACQUIRE,
                                      __HIP_MEMORY_SCOPE_WORKGROUP))
                __builtin_amdgcn_s_sleep(1);
            const double* vrow = (const double*)lds
                               + (size_t)(gt & (RING-1)) * VSLOTD
                               + (size_t)lane * VROWW;
            float* gdst = gdst0 + gt * 32;

            double vA[8], vB[8];
            PREF(vA, 0);
            PREF(vB, 1);         // in flight while chunk 0 scans
            SCANCH(vA, 0);
            PREF(vA, 2);         // in flight while chunk 1 scans
            SCANCH(vB, 1);
            PREF(vB, 3);         // in flight while chunk 2 scans
            SCANCH(vA, 2);
            SCANCH(vB, 3);

            __hip_atomic_store(consp, gt + 1, __ATOMIC_RELEASE,
                               __HIP_MEMORY_SCOPE_WORKGROUP);
        }
#undef SCANCH
#undef PREF
#undef STEP1
    }
}

extern "C" void kernel_launch(void* const* d_in, const int* in_sizes, int n_in,
                              void* d_out, int out_size, void* d_ws, size_t ws_size,
                              hipStream_t stream)
{
    const float* x  = (const float*)d_in[0];   // binary_input (1,32,1024,1024)
    const float* rk = (const float*)d_in[2];   // ref_kernel (100,)
    float* out = (float*)d_out;                // spikes (32,1024,1024) f32

    const int neurons = in_sizes[0] / T_LEN;   // 32768

    const double a_m   = std::exp(-0.1);       // exp(-dt/tau_mem)
    const double a_s   = std::exp(-0.2);       // exp(-dt/tau_syn)
    const double am100 = std::exp(-10.0);
    const double as100 = std::exp(-20.0);

    dim3 grid(neurons / 64), block(256);
    hipLaunchKernelGGL(spiking_fwd, grid, block, 0, stream,
                       x, rk, out, a_m, a_s, am100, as100);
}

// Round 13
// 138.031 us; speedup vs baseline: 1.0232x; 1.0232x over previous
//
#include <hip/hip_runtime.h>
#include <cmath>

// SpikingLayer forward — dynamic producer/consumer; coalesced producer loads
// via LDS staging; RING=3 (the r12 regression was RING=2 lockstep coupling,
// not the staging: r12 changed two variables, this round isolates one).
//
// vmem[t] = sum_{k<100} (am^k - as^k) x[t-k] (exact truncated-FIR via dual
// 1st-order f64 recurrences; time-chunked, 288-step zero-history warmup =
// mathematically exact after 100 steps). The nonlinear refractory scan is
// NEVER chunked: wave 3 runs it sequentially per neuron in f64, gold op
// order (rounds 5/8-12 all absmax 0.0 with this math).
//
//  * Producer tile loads COALESCED (8 lanes cover one neuron row's 128B ->
//    16 cache lines per instruction instead of 64), staged through a
//    per-producer LDS [64][36] f32 buffer, read back per-lane as b128.
//    (r12 proved this staging bit-exact.)
//  * RING=3: producers keep 2-3 tiles of slack ahead of the consumer
//    (r5/r11's RING=4 = 69-72us; r12's RING=2 = 141us lockstep).
//    50.7KB ring + 27.6KB stage + flags = 78.4KB -> 2 WG/CU (160KB pool).
//  * Consumer verbatim r11: 8-chunk register pipeline, direct global
//    scatter stores, r9-proven vmem bank swizzle.

#define T_LEN   1024
#define NT      32
#define RING    3
#define VROWW   33                        // doubles per vmem row (264 B)
#define VSLOTD  (64 * VROWW)              // 2112 doubles per ring slot
#define SROWW   36                        // stage row stride (floats)
#define STAGEW  (64 * SROWW)              // 2304 floats per stage buffer
#define LDS_STG (RING * VSLOTD * 8)       // 50688
#define LDS_FLG (LDS_STG + 3 * STAGEW * 4)// 78336
#define LDS_TOT (LDS_FLG + 33 * 4)        // 78468 B -> 2 WG/CU

__global__ __launch_bounds__(256, 2)
void spiking_fwd(const float* __restrict__ x, const float* __restrict__ rk,
                 float* __restrict__ out,
                 double a_m, double a_s, double am100, double as100)
{
    __shared__ __align__(16) unsigned char lds[LDS_TOT];
    int* const flags = (int*)(lds + LDS_FLG);   // [0..31] tile-ready
    int* const consp = flags + NT;              // tiles consumed

    const int tid = threadIdx.x, wid = tid >> 6, lane = tid & 63;
    const int n0 = blockIdx.x * 64;
    const unsigned vsw = (lane >> 4) & 3;       // vmem bank swizzle (r9-proven)

    if (tid <= NT) flags[tid] = 0;
    __syncthreads();

    if (wid < 3) {
        // ===================== producer (gold math) =====================
        // chunks [0,544) [544,800) [800,1024), warmup 288 for P1/P2
        int pwarm = 0, ptot = 0, pt0 = 0, gt0 = 0;
        if (wid == 0) { pt0 = 0;   ptot = 17; pwarm = 0; gt0 = 0;  }
        if (wid == 1) { pt0 = 256; ptot = 17; pwarm = 9; gt0 = 8;  }
        if (wid == 2) { pt0 = 512; ptot = 16; pwarm = 9; gt0 = 16; }
        const float* xbase = x + (size_t)n0 * T_LEN + pt0;   // block base
        const int rowq = lane >> 3, colq = lane & 7;
        float* const stg = (float*)(lds + LDS_STG) + wid * STAGEW;

        // stage tile 0 (coalesced: 8 lanes cover 128B of one neuron row)
        float4 g[8];
        #pragma unroll
        for (int j = 0; j < 8; ++j)
            g[j] = *(const float4*)(xbase + (size_t)(rowq + 8*j) * T_LEN + colq * 4);
        #pragma unroll
        for (int j = 0; j < 8; ++j)
            *(float4*)(stg + (rowq + 8*j) * SROWW + colq * 4) = g[j];

        double s_m = 0.0, s_s = 0.0;
        unsigned b0 = 0, b1 = 0, b2 = 0, b3 = 0;   // bit FIFO: tiles li-4..li-1

        for (int li = 0; li < ptot; ++li) {
            // per-lane read of own neuron's 32 steps (tile li)
            float4 xc4[8];
            const float* srow = stg + lane * SROWW;
            #pragma unroll
            for (int gq = 0; gq < 8; ++gq)
                xc4[gq] = *(const float4*)(srow + gq * 4);

            // issue coalesced prefetch of tile li+1 (lands under the chain)
            if (li + 1 < ptot) {
                #pragma unroll
                for (int j = 0; j < 8; ++j)
                    g[j] = *(const float4*)(xbase + (size_t)(rowq + 8*j) * T_LEN
                                            + (li + 1) * 32 + colq * 4);
            }

            // step t=pt0+li*32+k needs x[t-100]: k<4 -> tile li-4 bit 28+k,
            // k>=4 -> tile li-3 bit k-4.
            const unsigned wmask = (b0 >> 28) | (b1 << 4);
            unsigned bcur = 0;
            const int gt = gt0 + li;
            const float* xcf = (const float*)xc4;

            if (li >= pwarm) {
                while (gt - __hip_atomic_load(consp, __ATOMIC_ACQUIRE,
                                              __HIP_MEMORY_SCOPE_WORKGROUP) >= RING)
                    __builtin_amdgcn_s_sleep(1);
                double* vrow = (double*)lds
                             + (size_t)(gt % RING) * VSLOTD + (size_t)lane * VROWW;
                #pragma unroll
                for (int k = 0; k < 32; ++k) {
                    const float  xf = xcf[k];
                    const double xc = (double)xf;
                    const unsigned bd = (wmask >> k) & 1u;
                    s_m = fma(a_m, s_m, xc - (bd ? am100 : 0.0));
                    s_s = fma(a_s, s_s, xc - (bd ? as100 : 0.0));
                    vrow[k ^ vsw] = s_m - s_s;        // swizzled store
                    if (xf != 0.0f) bcur |= (1u << k);
                }
                __hip_atomic_store(&flags[gt], 1, __ATOMIC_RELEASE,
                                   __HIP_MEMORY_SCOPE_WORKGROUP);
            } else {                            // warmup tile
                #pragma unroll
                for (int k = 0; k < 32; ++k) {
                    const float  xf = xcf[k];
                    const double xc = (double)xf;
                    const unsigned bd = (wmask >> k) & 1u;
                    s_m = fma(a_m, s_m, xc - (bd ? am100 : 0.0));
                    s_s = fma(a_s, s_s, xc - (bd ? as100 : 0.0));
                    if (xf != 0.0f) bcur |= (1u << k);
                }
            }
            b0 = b1; b1 = b2; b2 = b3; b3 = bcur;

            // land the prefetched tile (tile li's stage already consumed)
            if (li + 1 < ptot) {
                #pragma unroll
                for (int j = 0; j < 8; ++j)
                    *(float4*)(stg + (rowq + 8*j) * SROWW + colq * 4) = g[j];
            }
        }
    } else {
        // ====== consumer: gold r-scan, 8-chunk pipeline, direct stores ======
        const double alpha = (double)rk[1] / (double)rk[0];
        double r = 0.0;
        float* const gdst0 = out + (size_t)(n0 + lane) * T_LEN;

#define STEP1(VMV, OO) do {                                   \
            double v_ = (VMV) - r;                            \
            double n_ = fmax(floor(v_), 0.0);                 \
            r = (r + n_) * alpha;                             \
            OO = (float)n_;                                   \
        } while (0)

#define PREF(VM, H) do {                                      \
            _Pragma("unroll")                                 \
            for (int k2 = 0; k2 < 8; ++k2)                    \
                (VM)[k2] = vrow[((H)*8 + k2) ^ vsw];          \
        } while (0)

#define SCANCH(VM, H) do {                                    \
            float4 o0, o1;                                    \
            STEP1((VM)[0], o0.x); STEP1((VM)[1], o0.y);       \
            STEP1((VM)[2], o0.z); STEP1((VM)[3], o0.w);       \
            STEP1((VM)[4], o1.x); STEP1((VM)[5], o1.y);       \
            STEP1((VM)[6], o1.z); STEP1((VM)[7], o1.w);       \
            *(float4*)(gdst + (H)*8)     = o0;                \
            *(float4*)(gdst + (H)*8 + 4) = o1;                \
        } while (0)

        for (int gt = 0; gt < NT; ++gt) {
            while (!__hip_atomic_load(&flags[gt], __ATOMIC_ACQUIRE,
                                      __HIP_MEMORY_SCOPE_WORKGROUP))
                __builtin_amdgcn_s_sleep(1);
            const double* vrow = (const double*)lds
                               + (size_t)(gt % RING) * VSLOTD
                               + (size_t)lane * VROWW;
            float* gdst = gdst0 + gt * 32;

            double vA[8], vB[8];
            PREF(vA, 0);
            PREF(vB, 1);         // in flight while chunk 0 scans
            SCANCH(vA, 0);
            PREF(vA, 2);         // in flight while chunk 1 scans
            SCANCH(vB, 1);
            PREF(vB, 3);         // in flight while chunk 2 scans
            SCANCH(vA, 2);
            SCANCH(vB, 3);

            __hip_atomic_store(consp, gt + 1, __ATOMIC_RELEASE,
                               __HIP_MEMORY_SCOPE_WORKGROUP);
        }
#undef SCANCH
#undef PREF
#undef STEP1
    }
}

extern "C" void kernel_launch(void* const* d_in, const int* in_sizes, int n_in,
                              void* d_out, int out_size, void* d_ws, size_t ws_size,
                              hipStream_t stream)
{
    const float* x  = (const float*)d_in[0];   // binary_input (1,32,1024,1024)
    const float* rk = (const float*)d_in[2];   // ref_kernel (100,)
    float* out = (float*)d_out;                // spikes (32,1024,1024) f32

    const int neurons = in_sizes[0] / T_LEN;   // 32768

    const double a_m   = std::exp(-0.1);       // exp(-dt/tau_mem)
    const double a_s   = std::exp(-0.2);       // exp(-dt/tau_syn)
    const double am100 = std::exp(-10.0);
    const double as100 = std::exp(-20.0);

    dim3 grid(neurons / 64), block(256);
    hipLaunchKernelGGL(spiking_fwd, grid, block, 0, stream,
                       x, rk, out, a_m, a_s, am100, as100);
}